// Round 1
// baseline (2228.170 us; speedup 1.0000x reference)
//
#include <hip/hip_runtime.h>
#include <stdint.h>
#include <stddef.h>

constexpr int T_STEPS  = 256;
constexpr int B_ROWS   = 4096;
constexpr int D_DIM    = 64;
constexpr int W_DIM    = 256;
constexpr int ROWS_PB  = 16;
constexpr int NTHREADS = 512;

typedef __attribute__((ext_vector_type(8))) __bf16 bf16x8;
typedef __attribute__((ext_vector_type(8))) short  short8;
typedef __attribute__((ext_vector_type(4))) float  f32x4;

__device__ __forceinline__ unsigned f2bf_bits(float f) {
    union { float f; unsigned u; } v; v.f = f;
    return (v.u + 0x7FFFu + ((v.u >> 16) & 1u)) >> 16;   // RTNE
}

__device__ __forceinline__ float softplus_f(float x) {
    float e = __expf(-fabsf(x));
    return fmaxf(x, 0.0f) + __logf(1.0f + e);
}

// B-fragment gather: lane holds w[f][kb..kb+7] as bf16 (16x16x32 B-operand slice)
__device__ __forceinline__ bf16x8 load_wfrag(const float* __restrict__ wg, int ldk, int f, int kb) {
    const float* p = wg + (size_t)f * ldk + kb;
    short8 s;
#pragma unroll
    for (int i = 0; i < 8; ++i) s[i] = (short)f2bf_bits(p[i]);
    return __builtin_bit_cast(bf16x8, s);
}

__global__ __launch_bounds__(NTHREADS, 2) void node_rk3_kernel(
    const float* __restrict__ ts,
    const float* __restrict__ y0,
    const float* __restrict__ w0, const float* __restrict__ b0,
    const float* __restrict__ w1, const float* __restrict__ b1,
    const float* __restrict__ w2, const float* __restrict__ b2,
    const float* __restrict__ w3, const float* __restrict__ b3,
    float* __restrict__ out)
{
    // LDS: swizzled bf16 activations + f32 state
    __shared__ __align__(16) short hs0[ROWS_PB][W_DIM];   // 8 KB
    __shared__ __align__(16) short hs1[ROWS_PB][W_DIM];   // 8 KB
    __shared__ __align__(16) short ybf[ROWS_PB][D_DIM];   // 2 KB (bf16 MLP input)
    __shared__ float yf[ROWS_PB][D_DIM];                  // 4 KB (f32 state)
    __shared__ float kbuf[3][ROWS_PB][D_DIM];             // 12 KB (k1,k2,k3)

    const int tid  = threadIdx.x;
    const int lane = tid & 63;
    const int wid  = tid >> 6;
    const int lr   = lane & 15;   // A row / C-D col / B col index
    const int lg   = lane >> 4;   // lane group 0..3
    const int row0 = blockIdx.x * ROWS_PB;

    const int fb = wid * 32;        // hidden-feature base owned by this wave
    const int f3 = (wid & 3) * 16;  // layer-3 feature base (waves 0..3 active)

    // ---- persistent register-resident weight fragments (~176 VGPR) ----
    bf16x8 w0f[2][2], w1f[2][8], w2f[2][8], w3f[8];
#pragma unroll
    for (int nt = 0; nt < 2; ++nt) {
        const int f = fb + nt * 16 + lr;
#pragma unroll
        for (int kc = 0; kc < 2; ++kc) w0f[nt][kc] = load_wfrag(w0, D_DIM, f, kc * 32 + lg * 8);
#pragma unroll
        for (int kc = 0; kc < 8; ++kc) w1f[nt][kc] = load_wfrag(w1, W_DIM, f, kc * 32 + lg * 8);
#pragma unroll
        for (int kc = 0; kc < 8; ++kc) w2f[nt][kc] = load_wfrag(w2, W_DIM, f, kc * 32 + lg * 8);
    }
#pragma unroll
    for (int kc = 0; kc < 8; ++kc) w3f[kc] = load_wfrag(w3, W_DIM, f3 + lr, kc * 32 + lg * 8);

    const float bv0[2] = { b0[fb + lr], b0[fb + 16 + lr] };
    const float bv1[2] = { b1[fb + lr], b1[fb + 16 + lr] };
    const float bv2[2] = { b2[fb + lr], b2[fb + 16 + lr] };
    const float bv3 = b3[f3 + lr];

    const float dt = ts[1] - ts[0];

    // ---- initial state ----
    for (int i = tid; i < ROWS_PB * D_DIM; i += NTHREADS) {
        const int r = i >> 6, d = i & 63;
        const float v = y0[(size_t)(row0 + r) * D_DIM + d];
        yf[r][d] = v;
        ybf[r][d ^ ((r & 7) << 3)] = (short)f2bf_bits(v);
    }
    __syncthreads();

    for (int t = 0; t < T_STEPS; ++t) {
#pragma unroll
        for (int c = 0; c < 3; ++c) {
            // ---------- layer 0: ybf[16][64] -> hs0 ----------
            {
                f32x4 acc0 = {0.f, 0.f, 0.f, 0.f}, acc1 = {0.f, 0.f, 0.f, 0.f};
#pragma unroll
                for (int kc = 0; kc < 2; ++kc) {
                    const int col = (kc * 32 + lg * 8) ^ ((lr & 7) << 3);
                    const bf16x8 a = *reinterpret_cast<const bf16x8*>(&ybf[lr][col]);
                    acc0 = __builtin_amdgcn_mfma_f32_16x16x32_bf16(a, w0f[0][kc], acc0, 0, 0, 0);
                    acc1 = __builtin_amdgcn_mfma_f32_16x16x32_bf16(a, w0f[1][kc], acc1, 0, 0, 0);
                }
#pragma unroll
                for (int j = 0; j < 4; ++j) {
                    const int r = lg * 4 + j;
                    hs0[r][(fb + lr)      ^ ((r & 7) << 3)] = (short)f2bf_bits(softplus_f(acc0[j] + bv0[0]));
                    hs0[r][(fb + 16 + lr) ^ ((r & 7) << 3)] = (short)f2bf_bits(softplus_f(acc1[j] + bv0[1]));
                }
            }
            __syncthreads();
            // ---------- layer 1: hs0 -> hs1 ----------
            {
                f32x4 acc0 = {0.f, 0.f, 0.f, 0.f}, acc1 = {0.f, 0.f, 0.f, 0.f};
#pragma unroll
                for (int kc = 0; kc < 8; ++kc) {
                    const int col = (kc * 32 + lg * 8) ^ ((lr & 7) << 3);
                    const bf16x8 a = *reinterpret_cast<const bf16x8*>(&hs0[lr][col]);
                    acc0 = __builtin_amdgcn_mfma_f32_16x16x32_bf16(a, w1f[0][kc], acc0, 0, 0, 0);
                    acc1 = __builtin_amdgcn_mfma_f32_16x16x32_bf16(a, w1f[1][kc], acc1, 0, 0, 0);
                }
#pragma unroll
                for (int j = 0; j < 4; ++j) {
                    const int r = lg * 4 + j;
                    hs1[r][(fb + lr)      ^ ((r & 7) << 3)] = (short)f2bf_bits(softplus_f(acc0[j] + bv1[0]));
                    hs1[r][(fb + 16 + lr) ^ ((r & 7) << 3)] = (short)f2bf_bits(softplus_f(acc1[j] + bv1[1]));
                }
            }
            __syncthreads();
            // ---------- layer 2: hs1 -> hs0 ----------
            {
                f32x4 acc0 = {0.f, 0.f, 0.f, 0.f}, acc1 = {0.f, 0.f, 0.f, 0.f};
#pragma unroll
                for (int kc = 0; kc < 8; ++kc) {
                    const int col = (kc * 32 + lg * 8) ^ ((lr & 7) << 3);
                    const bf16x8 a = *reinterpret_cast<const bf16x8*>(&hs1[lr][col]);
                    acc0 = __builtin_amdgcn_mfma_f32_16x16x32_bf16(a, w2f[0][kc], acc0, 0, 0, 0);
                    acc1 = __builtin_amdgcn_mfma_f32_16x16x32_bf16(a, w2f[1][kc], acc1, 0, 0, 0);
                }
#pragma unroll
                for (int j = 0; j < 4; ++j) {
                    const int r = lg * 4 + j;
                    hs0[r][(fb + lr)      ^ ((r & 7) << 3)] = (short)f2bf_bits(softplus_f(acc0[j] + bv2[0]));
                    hs0[r][(fb + 16 + lr) ^ ((r & 7) << 3)] = (short)f2bf_bits(softplus_f(acc1[j] + bv2[1]));
                }
            }
            __syncthreads();
            // ---------- layer 3: hs0 -> kbuf[c] (f32, no activation) ----------
            if (wid < 4) {
                f32x4 acc = {0.f, 0.f, 0.f, 0.f};
#pragma unroll
                for (int kc = 0; kc < 8; ++kc) {
                    const int col = (kc * 32 + lg * 8) ^ ((lr & 7) << 3);
                    const bf16x8 a = *reinterpret_cast<const bf16x8*>(&hs0[lr][col]);
                    acc = __builtin_amdgcn_mfma_f32_16x16x32_bf16(a, w3f[kc], acc, 0, 0, 0);
                }
#pragma unroll
                for (int j = 0; j < 4; ++j) {
                    kbuf[c][lg * 4 + j][f3 + lr] = acc[j] + bv3;
                }
            }
            __syncthreads();
            // ---------- RK3 state updates (f32) ----------
            if (c < 2) {
                const float coef = (c == 0) ? 0.5f : 0.75f;
                for (int i = tid; i < ROWS_PB * D_DIM; i += NTHREADS) {
                    const int r = i >> 6, d = i & 63;
                    const float v = yf[r][d] + coef * kbuf[c][r][d];
                    ybf[r][d ^ ((r & 7) << 3)] = (short)f2bf_bits(v);
                }
            } else {
                for (int i = tid; i < ROWS_PB * D_DIM; i += NTHREADS) {
                    const int r = i >> 6, d = i & 63;
                    const float v = yf[r][d]
                        + dt * ( (2.0f / 9.0f) * kbuf[0][r][d]
                               + (1.0f / 3.0f) * kbuf[1][r][d]
                               + (4.0f / 9.0f) * kbuf[2][r][d] );
                    yf[r][d] = v;
                    ybf[r][d ^ ((r & 7) << 3)] = (short)f2bf_bits(v);
                    out[((size_t)t * B_ROWS + row0 + r) * D_DIM + d] = v;
                }
            }
            __syncthreads();
        }
    }
}

extern "C" void kernel_launch(void* const* d_in, const int* in_sizes, int n_in,
                              void* d_out, int out_size, void* d_ws, size_t ws_size,
                              hipStream_t stream) {
    const float* ts = (const float*)d_in[0];
    const float* y0 = (const float*)d_in[1];
    const float* w0 = (const float*)d_in[2];
    const float* b0 = (const float*)d_in[3];
    const float* w1 = (const float*)d_in[4];
    const float* b1 = (const float*)d_in[5];
    const float* w2 = (const float*)d_in[6];
    const float* b2 = (const float*)d_in[7];
    const float* w3 = (const float*)d_in[8];
    const float* b3 = (const float*)d_in[9];
    float* out = (float*)d_out;

    hipLaunchKernelGGL(node_rk3_kernel,
                       dim3(B_ROWS / ROWS_PB), dim3(NTHREADS), 0, stream,
                       ts, y0, w0, b0, w1, b1, w2, b2, w3, b3, out);
}

// Round 2
// 1670.777 us; speedup vs baseline: 1.3336x; 1.3336x over previous
//
#include <hip/hip_runtime.h>
#include <stdint.h>
#include <stddef.h>

constexpr int T_STEPS  = 256;
constexpr int B_ROWS   = 4096;
constexpr int D_DIM    = 64;
constexpr int W_DIM    = 256;
constexpr int ROWS_PB  = 16;
constexpr int NTHREADS = 512;

typedef __attribute__((ext_vector_type(8))) __bf16 bf16x8;
typedef __attribute__((ext_vector_type(8))) short  short8;
typedef __attribute__((ext_vector_type(4))) float  f32x4;

__device__ __forceinline__ unsigned f2bf_bits(float f) {
    union { float f; unsigned u; } v; v.f = f;
    return (v.u + 0x7FFFu + ((v.u >> 16) & 1u)) >> 16;   // RTNE
}

__device__ __forceinline__ uint32_t cvt_pk_bf16(float lo, float hi) {
    uint32_t r;
    asm("v_cvt_pk_bf16_f32 %0, %1, %2" : "=v"(r) : "v"(lo), "v"(hi));
    return r;
}

__device__ __forceinline__ float softplus_f(float x) {
    float e = __builtin_amdgcn_exp2f(-fabsf(x) * 1.44269504f);
    float l = __builtin_amdgcn_logf(1.0f + e);           // log2(1+e), e in (0,1]
    return fmaxf(x, 0.0f) + 0.69314718f * l;
}

// Permuted B-fragment to match interleaved-pair activation packing:
// elem j holds w[f][kcbase + lg*4 + (j>>1) + 16*(j&1)]
__device__ __forceinline__ bf16x8 load_wfrag(const float* __restrict__ wg, int ldk,
                                             int f, int kcbase, int lg) {
    short8 s;
#pragma unroll
    for (int j = 0; j < 8; ++j) {
        const int k = kcbase + lg * 4 + (j >> 1) + ((j & 1) << 4);
        s[j] = (short)f2bf_bits(wg[(size_t)f * ldk + k]);
    }
    return __builtin_bit_cast(bf16x8, s);
}

// One hidden layer: src row (packed dwords) -> dst (packed dwords), softplus applied.
template<int NKC>
__device__ __forceinline__ void mlp_layer(const uint32_t* __restrict__ srow,
                                          uint32_t* __restrict__ dst,
                                          const bf16x8* wf0, const bf16x8* wf1,
                                          float b0v, float b1v,
                                          int lr, int lg, int fbdw)
{
    const int swz = (lr & 7) << 2;
    f32x4 a0 = {b0v, b0v, b0v, b0v};
    f32x4 a1 = {b1v, b1v, b1v, b1v};
#pragma unroll
    for (int kc = 0; kc < NKC; ++kc) {
        const bf16x8 a = *reinterpret_cast<const bf16x8*>(srow + ((kc * 16 + lg * 4) ^ swz));
        a0 = __builtin_amdgcn_mfma_f32_16x16x32_bf16(a, wf0[kc], a0, 0, 0, 0);
        a1 = __builtin_amdgcn_mfma_f32_16x16x32_bf16(a, wf1[kc], a1, 0, 0, 0);
    }
#pragma unroll
    for (int j = 0; j < 4; ++j) {
        const int r = lg * 4 + j;
        dst[(size_t)r * 128 + ((fbdw + lr) ^ ((r & 7) << 2))] =
            cvt_pk_bf16(softplus_f(a0[j]), softplus_f(a1[j]));
    }
}

__global__ __launch_bounds__(NTHREADS, 2) void node_rk3_kernel(
    const float* __restrict__ ts,
    const float* __restrict__ y0,
    const float* __restrict__ w0, const float* __restrict__ b0,
    const float* __restrict__ w1, const float* __restrict__ b1,
    const float* __restrict__ w2, const float* __restrict__ b2,
    const float* __restrict__ w3, const float* __restrict__ b3,
    float* __restrict__ out)
{
    __shared__ __align__(16) uint32_t hs0[ROWS_PB][128];  // 8 KB packed bf16 pairs
    __shared__ __align__(16) uint32_t hs1[ROWS_PB][128];  // 8 KB
    __shared__ __align__(16) uint32_t ybf[ROWS_PB][32];   // 2 KB packed y

    const int tid  = threadIdx.x;
    const int lane = tid & 63;
    const int wid  = tid >> 6;
    const int lr   = lane & 15;
    const int lg   = lane >> 4;
    const int row0 = blockIdx.x * ROWS_PB;
    const int fbdw = wid * 16;           // dword base of this wave's 32-feature slice

    // ---- persistent register-resident weight fragments ----
    bf16x8 w0f[2][2], w1f[2][8], w2f[2][8], w3f[8];
#pragma unroll
    for (int nt = 0; nt < 2; ++nt) {
        const int f = wid * 32 + nt * 16 + lr;
#pragma unroll
        for (int kc = 0; kc < 2; ++kc) w0f[nt][kc] = load_wfrag(w0, D_DIM, f, kc * 32, lg);
#pragma unroll
        for (int kc = 0; kc < 8; ++kc) w1f[nt][kc] = load_wfrag(w1, W_DIM, f, kc * 32, lg);
#pragma unroll
        for (int kc = 0; kc < 8; ++kc) w2f[nt][kc] = load_wfrag(w2, W_DIM, f, kc * 32, lg);
    }
    const int f3 = (wid & 3) * 16;       // layer-3 feature base (waves 0..3 active)
#pragma unroll
    for (int kc = 0; kc < 8; ++kc) w3f[kc] = load_wfrag(w3, W_DIM, f3 + lr, kc * 32, lg);

    const float bA0 = b0[wid * 32 + lr], bB0 = b0[wid * 32 + 16 + lr];
    const float bA1 = b1[wid * 32 + lr], bB1 = b1[wid * 32 + 16 + lr];
    const float bA2 = b2[wid * 32 + lr], bB2 = b2[wid * 32 + 16 + lr];
    const float bv3 = b3[f3 + lr];

    const float dt = ts[1] - ts[0];

    // ---- per-lane state (waves 0..3): y[r=lg*4+j][d=f3+lr] ----
    float yreg[4], k1r[4], k2r[4];
#pragma unroll
    for (int j = 0; j < 4; ++j)
        yreg[j] = y0[(size_t)(row0 + lg * 4 + j) * D_DIM + f3 + lr];
#pragma unroll
    for (int j = 0; j < 4; ++j) { k1r[j] = 0.f; k2r[j] = 0.f; }

    // ---- initial packed ybf ----
    for (int i = tid; i < ROWS_PB * 32; i += NTHREADS) {
        const int r = i >> 5, c32 = i & 31, kb = c32 >> 4, u = c32 & 15;
        const float* yr = y0 + (size_t)(row0 + r) * D_DIM;
        ybf[r][(kb * 16 + u) ^ ((r & 7) << 2)] = cvt_pk_bf16(yr[kb * 32 + u], yr[kb * 32 + 16 + u]);
    }
    __syncthreads();

    for (int t = 0; t < T_STEPS; ++t) {
#pragma unroll
        for (int c = 0; c < 3; ++c) {
            mlp_layer<2>(&ybf[lr][0], &hs0[0][0], w0f[0], w0f[1], bA0, bB0, lr, lg, fbdw);
            __syncthreads();
            mlp_layer<8>(&hs0[lr][0], &hs1[0][0], w1f[0], w1f[1], bA1, bB1, lr, lg, fbdw);
            __syncthreads();
            mlp_layer<8>(&hs1[lr][0], &hs0[0][0], w2f[0], w2f[1], bA2, bB2, lr, lg, fbdw);
            __syncthreads();
            // ---------- layer 3 + in-register RK update (waves 0..3) ----------
            if (wid < 4) {
                const int swz = (lr & 7) << 2;
                f32x4 acc = {bv3, bv3, bv3, bv3};
#pragma unroll
                for (int kc = 0; kc < 8; ++kc) {
                    const bf16x8 a = *reinterpret_cast<const bf16x8*>(&hs0[lr][(kc * 16 + lg * 4) ^ swz]);
                    acc = __builtin_amdgcn_mfma_f32_16x16x32_bf16(a, w3f[kc], acc, 0, 0, 0);
                }
                const int kb = wid >> 1, hi = wid & 1;
#pragma unroll
                for (int j = 0; j < 4; ++j) {
                    const int r = lg * 4 + j;
                    float v;
                    if (c == 0)      { k1r[j] = acc[j]; v = fmaf(0.5f,  acc[j], yreg[j]); }
                    else if (c == 1) { k2r[j] = acc[j]; v = fmaf(0.75f, acc[j], yreg[j]); }
                    else {
                        v = yreg[j] + dt * ((2.0f / 9.0f) * k1r[j]
                                          + (1.0f / 3.0f) * k2r[j]
                                          + (4.0f / 9.0f) * acc[j]);
                        yreg[j] = v;
                        out[((size_t)t * B_ROWS + row0 + r) * D_DIM + f3 + lr] = v;
                    }
                    uint16_t* p = (uint16_t*)&ybf[r][(kb * 16 + lr) ^ ((r & 7) << 2)];
                    p[hi] = (uint16_t)cvt_pk_bf16(v, v);
                }
            }
            __syncthreads();
        }
    }
}

extern "C" void kernel_launch(void* const* d_in, const int* in_sizes, int n_in,
                              void* d_out, int out_size, void* d_ws, size_t ws_size,
                              hipStream_t stream) {
    const float* ts = (const float*)d_in[0];
    const float* y0 = (const float*)d_in[1];
    const float* w0 = (const float*)d_in[2];
    const float* b0 = (const float*)d_in[3];
    const float* w1 = (const float*)d_in[4];
    const float* b1 = (const float*)d_in[5];
    const float* w2 = (const float*)d_in[6];
    const float* b2 = (const float*)d_in[7];
    const float* w3 = (const float*)d_in[8];
    const float* b3 = (const float*)d_in[9];
    float* out = (float*)d_out;

    hipLaunchKernelGGL(node_rk3_kernel,
                       dim3(B_ROWS / ROWS_PB), dim3(NTHREADS), 0, stream,
                       ts, y0, w0, b0, w1, b1, w2, b2, w3, b3, out);
}

// Round 4
// 1398.814 us; speedup vs baseline: 1.5929x; 1.1944x over previous
//
#include <hip/hip_runtime.h>
#include <stdint.h>
#include <stddef.h>

constexpr int T_STEPS  = 256;
constexpr int B_ROWS   = 4096;
constexpr int D_DIM    = 64;
constexpr int W_DIM    = 256;
constexpr int ROWS_PB  = 16;
constexpr int NTHREADS = 512;

constexpr int HS_LD = 132;   // hidden-act LDS row stride (dwords): 132 mod 32 = 4 -> bank stagger
constexpr int YB_LD = 36;    // y-act LDS row stride (dwords):       36 mod 32 = 4

constexpr float LOG2E = 1.44269504088896f;
constexpr float LN2   = 0.693147180559945f;

typedef __attribute__((ext_vector_type(8))) __bf16 bf16x8;
typedef __attribute__((ext_vector_type(8))) short  short8;
typedef __attribute__((ext_vector_type(4))) float  f32x4;

__device__ __forceinline__ unsigned f2bf_bits(float f) {
    union { float f; unsigned u; } v; v.f = f;
    return (v.u + 0x7FFFu + ((v.u >> 16) & 1u)) >> 16;   // RTNE
}

__device__ __forceinline__ uint32_t cvt_pk_bf16(float lo, float hi) {
    uint32_t r;
    asm("v_cvt_pk_bf16_f32 %0, %1, %2" : "=v"(r) : "v"(lo), "v"(hi));
    return r;
}

// Overflow-safe softplus in log2 domain: g(u) = max(u,0) + log2(1 + 2^-|u|).
// exp2 argument is always <= 0 -> no overflow for any finite u; log2 input in [1,2].
// -|u| folds into exp2's free input modifiers (neg+abs).
__device__ __forceinline__ float act_g(float u) {
    float e = __builtin_amdgcn_exp2f(-fabsf(u));
    return fmaxf(u, 0.0f) + __builtin_amdgcn_logf(1.0f + e);
}

// B-fragment, interleaved-pair permutation: elem j <-> k = kcb + lg*4 + (j>>1) + 16*(j&1)
// Vectorized: two float4 loads (k runs [kcb+lg*4, +4) and [kcb+16+lg*4, +4)), scaled.
__device__ __forceinline__ bf16x8 load_wfrag(const float* __restrict__ wg, int ldk,
                                             int f, int kcb, int lg, float scale) {
    const float4 a = *reinterpret_cast<const float4*>(wg + (size_t)f * ldk + kcb + lg * 4);
    const float4 b = *reinterpret_cast<const float4*>(wg + (size_t)f * ldk + kcb + 16 + lg * 4);
    short8 s;
    s[0] = (short)f2bf_bits(a.x * scale); s[1] = (short)f2bf_bits(b.x * scale);
    s[2] = (short)f2bf_bits(a.y * scale); s[3] = (short)f2bf_bits(b.y * scale);
    s[4] = (short)f2bf_bits(a.z * scale); s[5] = (short)f2bf_bits(b.z * scale);
    s[6] = (short)f2bf_bits(a.w * scale); s[7] = (short)f2bf_bits(b.w * scale);
    return __builtin_bit_cast(bf16x8, s);
}

// One hidden layer. src = &buf[lr][lg*4] (b128 reads at +kc*16 dwords, imm offsets);
// dst = &buf[lg*4][fbdw+lr] (b32 writes at +j*HS_LD, imm offsets).
template<int NKC>
__device__ __forceinline__ void mlp_layer(const uint32_t* __restrict__ src,
                                          uint32_t* __restrict__ dst,
                                          const bf16x8* wf0, const bf16x8* wf1,
                                          float b0v, float b1v)
{
    f32x4 a0 = {b0v, b0v, b0v, b0v};
    f32x4 a1 = {b1v, b1v, b1v, b1v};
#pragma unroll
    for (int kc = 0; kc < NKC; ++kc) {
        const bf16x8 a = *reinterpret_cast<const bf16x8*>(src + kc * 16);
        a0 = __builtin_amdgcn_mfma_f32_16x16x32_bf16(a, wf0[kc], a0, 0, 0, 0);
        a1 = __builtin_amdgcn_mfma_f32_16x16x32_bf16(a, wf1[kc], a1, 0, 0, 0);
    }
#pragma unroll
    for (int j = 0; j < 4; ++j)
        dst[j * HS_LD] = cvt_pk_bf16(act_g(a0[j]), act_g(a1[j]));
}

__global__ __launch_bounds__(NTHREADS, 2) void node_rk3_kernel(
    const float* __restrict__ ts,
    const float* __restrict__ y0,
    const float* __restrict__ w0, const float* __restrict__ b0,
    const float* __restrict__ w1, const float* __restrict__ b1,
    const float* __restrict__ w2, const float* __restrict__ b2,
    const float* __restrict__ w3, const float* __restrict__ b3,
    float* __restrict__ out)
{
    __shared__ __align__(16) uint32_t hs0[ROWS_PB][HS_LD];
    __shared__ __align__(16) uint32_t hs1[ROWS_PB][HS_LD];
    __shared__ __align__(16) uint32_t ybf[ROWS_PB][YB_LD];

    const int tid  = threadIdx.x;
    const int lane = tid & 63;
    const int wid  = tid >> 6;
    const int lr   = lane & 15;
    const int lg   = lane >> 4;
    const int row0 = blockIdx.x * ROWS_PB;
    const int fbdw = wid * 16;           // dword base of this wave's 32-feat slice

    // ---- persistent register-resident weight fragments (pre-scaled) ----
    bf16x8 w0f[2][2], w1f[2][8], w2f[2][8], w3f[8];
#pragma unroll
    for (int nt = 0; nt < 2; ++nt) {
        const int f = wid * 32 + nt * 16 + lr;
#pragma unroll
        for (int kc = 0; kc < 2; ++kc) w0f[nt][kc] = load_wfrag(w0, D_DIM, f, kc * 32, lg, LOG2E);
#pragma unroll
        for (int kc = 0; kc < 8; ++kc) w1f[nt][kc] = load_wfrag(w1, W_DIM, f, kc * 32, lg, 1.0f);
#pragma unroll
        for (int kc = 0; kc < 8; ++kc) w2f[nt][kc] = load_wfrag(w2, W_DIM, f, kc * 32, lg, 1.0f);
    }
    const int f3 = (wid & 3) * 16;       // layer-3 feature base (waves 0..3 active)
#pragma unroll
    for (int kc = 0; kc < 8; ++kc) w3f[kc] = load_wfrag(w3, W_DIM, f3 + lr, kc * 32, lg, LN2);

    const float bA0 = LOG2E * b0[wid * 32 + lr], bB0 = LOG2E * b0[wid * 32 + 16 + lr];
    const float bA1 = LOG2E * b1[wid * 32 + lr], bB1 = LOG2E * b1[wid * 32 + 16 + lr];
    const float bA2 = LOG2E * b2[wid * 32 + lr], bB2 = LOG2E * b2[wid * 32 + 16 + lr];
    const float bv3 = b3[f3 + lr];

    const float dt = ts[1] - ts[0];

    // ---- per-thread LDS base pointers (all later accesses use imm offsets) ----
    const uint32_t* pA_y  = &ybf[lr][lg * 4];
    const uint32_t* pA_h0 = &hs0[lr][lg * 4];
    const uint32_t* pA_h1 = &hs1[lr][lg * 4];
    uint32_t* pW_h0 = &hs0[lg * 4][fbdw + lr];
    uint32_t* pW_h1 = &hs1[lg * 4][fbdw + lr];
    const int kb = wid >> 1, hi = wid & 1;          // ybf halfword write geometry (waves 0..3)
    uint16_t* pYW = (uint16_t*)&ybf[0][0] + ((size_t)(lg * 4) * YB_LD + kb * 16 + lr) * 2 + hi;

    // ---- per-lane state (waves 0..3): y[r=lg*4+j][d=f3+lr] ----
    float yreg[4], k1r[4], k2r[4], vst[4];
#pragma unroll
    for (int j = 0; j < 4; ++j) {
        yreg[j] = y0[(size_t)(row0 + lg * 4 + j) * D_DIM + f3 + lr];
        k1r[j] = 0.f; k2r[j] = 0.f; vst[j] = 0.f;
    }

    // ---- initial packed ybf ----
    for (int i = tid; i < ROWS_PB * 32; i += NTHREADS) {
        const int r = i >> 5, c32 = i & 31, kbi = c32 >> 4, u = c32 & 15;
        const float* yr = y0 + (size_t)(row0 + r) * D_DIM;
        ybf[r][kbi * 16 + u] = cvt_pk_bf16(yr[kbi * 32 + u], yr[kbi * 32 + 16 + u]);
    }
    __syncthreads();

    for (int t = 0; t < T_STEPS; ++t) {
        // deferred global store of step t-1 (overlaps with L0 compute of step t)
        if (wid < 4 && t > 0) {
#pragma unroll
            for (int j = 0; j < 4; ++j)
                out[((size_t)(t - 1) * B_ROWS + row0 + lg * 4 + j) * D_DIM + f3 + lr] = vst[j];
        }
#pragma unroll
        for (int c = 0; c < 3; ++c) {
            mlp_layer<2>(pA_y,  pW_h0, w0f[0], w0f[1], bA0, bB0);
            __syncthreads();
            mlp_layer<8>(pA_h0, pW_h1, w1f[0], w1f[1], bA1, bB1);
            __syncthreads();
            mlp_layer<8>(pA_h1, pW_h0, w2f[0], w2f[1], bA2, bB2);
            __syncthreads();
            // ---------- layer 3 + in-register RK update (waves 0..3) ----------
            if (wid < 4) {
                f32x4 acc = {bv3, bv3, bv3, bv3};
#pragma unroll
                for (int kc = 0; kc < 8; ++kc) {
                    const bf16x8 a = *reinterpret_cast<const bf16x8*>(pA_h0 + kc * 16);
                    acc = __builtin_amdgcn_mfma_f32_16x16x32_bf16(a, w3f[kc], acc, 0, 0, 0);
                }
#pragma unroll
                for (int j = 0; j < 4; ++j) {
                    float v;
                    if (c == 0)      { k1r[j] = acc[j]; v = fmaf(0.5f,  acc[j], yreg[j]); }
                    else if (c == 1) { k2r[j] = acc[j]; v = fmaf(0.75f, acc[j], yreg[j]); }
                    else {
                        v = yreg[j] + dt * ((2.0f / 9.0f) * k1r[j]
                                          + (1.0f / 3.0f) * k2r[j]
                                          + (4.0f / 9.0f) * acc[j]);
                        yreg[j] = v;
                        vst[j]  = v;
                    }
                    pYW[j * YB_LD * 2] = (uint16_t)cvt_pk_bf16(v, v);
                }
            }
            __syncthreads();
        }
    }
    // final step's store
    if (wid < 4) {
#pragma unroll
        for (int j = 0; j < 4; ++j)
            out[((size_t)(T_STEPS - 1) * B_ROWS + row0 + lg * 4 + j) * D_DIM + f3 + lr] = vst[j];
    }
}

extern "C" void kernel_launch(void* const* d_in, const int* in_sizes, int n_in,
                              void* d_out, int out_size, void* d_ws, size_t ws_size,
                              hipStream_t stream) {
    const float* ts = (const float*)d_in[0];
    const float* y0 = (const float*)d_in[1];
    const float* w0 = (const float*)d_in[2];
    const float* b0 = (const float*)d_in[3];
    const float* w1 = (const float*)d_in[4];
    const float* b1 = (const float*)d_in[5];
    const float* w2 = (const float*)d_in[6];
    const float* b2 = (const float*)d_in[7];
    const float* w3 = (const float*)d_in[8];
    const float* b3 = (const float*)d_in[9];
    float* out = (float*)d_out;

    hipLaunchKernelGGL(node_rk3_kernel,
                       dim3(B_ROWS / ROWS_PB), dim3(NTHREADS), 0, stream,
                       ts, y0, w0, b0, w1, b1, w2, b2, w3, b3, out);
}